// Round 14
// baseline (75.849 us; speedup 1.0000x reference)
//
#include <hip/hip_runtime.h>
#include <hip/hip_bf16.h>
#include <stdint.h>

#define NB 8192
#define DK 256
// gamma * log2(e): epilogue uses native exp2
#define GSCALE 14.426950408889634f

typedef short short8 __attribute__((ext_vector_type(8)));
typedef float f32x4 __attribute__((ext_vector_type(4)));

__device__ __forceinline__ unsigned short f32_to_bf16(float f) {
  uint32_t u = __builtin_bit_cast(uint32_t, f);
  u += 0x7FFFu + ((u >> 16) & 1u);   // RNE
  return (unsigned short)(u >> 16);
}

// Normalize (gamma*log2e folded into e side) AND write in PACKED MFMA-fragment
// layout: fragment (row-panel p = r>>4, ks = k>>5) is a contiguous 1-KB chunk;
// lane l owns bytes l*16..+16 = row p*16+(r&15), k = ks*32 + (l>>4)*8 ..+8.
// packed_byte(r,k) = (r>>4)*8192 + (k>>5)*1024 + ((k>>3)&3)*256 + (r&15)*16 + (k&7)*2.
// Blocks 0..15 also zero d_out (replaces hipMemsetAsync).
__global__ __launch_bounds__(256) void normpack_kernel(const float* __restrict__ e,
                                                       const float* __restrict__ v,
                                                       unsigned short* __restrict__ apk,
                                                       unsigned short* __restrict__ vpk,
                                                       float* __restrict__ out) {
  if (blockIdx.x < 16) {
    float4 z = {0.f, 0.f, 0.f, 0.f};
    reinterpret_cast<float4*>(out)[blockIdx.x * 256 + threadIdx.x] = z;
  }
  int wave = threadIdx.x >> 6;
  int lane = threadIdx.x & 63;
  int row = blockIdx.x * 4 + wave;          // 0..16383
  const float* src;
  unsigned short* dstbase;
  float mul;
  if (row < NB) {
    src = e + (size_t)row * DK; dstbase = apk; mul = GSCALE;
  } else {
    row -= NB;
    src = v + (size_t)row * DK; dstbase = vpk; mul = 1.0f;
  }
  float4 x = reinterpret_cast<const float4*>(src)[lane];   // k = 4*lane .. +3
  float ss = x.x * x.x + x.y * x.y + x.z * x.z + x.w * x.w;
  #pragma unroll
  for (int off = 32; off >= 1; off >>= 1) ss += __shfl_xor(ss, off);
  float s = mul / fmaxf(sqrtf(ss), 1e-8f);
  ushort4 o;
  o.x = f32_to_bf16(x.x * s);
  o.y = f32_to_bf16(x.y * s);
  o.z = f32_to_bf16(x.z * s);
  o.w = f32_to_bf16(x.w * s);
  size_t off = (size_t)(row >> 4) * 8192 + (size_t)(lane >> 3) * 1024 +
               ((lane >> 1) & 3) * 256 + (row & 15) * 16 + (lane & 1) * 8;
  *reinterpret_cast<ushort4*>((char*)dstbase + off) = o;
}

// R13 structure with the wave tile split 64x64 -> 32x64 to HALVE the per-wave
// register footprint (acc 64->32 AGPR; ~100 unified regs -> 5 waves/SIMD vs
// 3): per-CU pipe totals are invariant, TLP doubles -- attacking the measured
// deficit (28% occupancy, no pipe saturated). Block = 64 rows x 256 cols,
// 8 waves (2 row-halves x 4 col-quarters); A panel (32 KB packed) staged to
// LDS once (linear copy, conflict-free reads); B frags = coalesced 1-KB loads
// through the proven static ping-pong S[2][4]; one K=256 pass; no in-loop
// barriers. Row/col partials merge via ds_add_f32 (LDS atomics); global
// atomics once per block in the tail.
__global__ __launch_bounds__(512, 4) void score_kernel(const unsigned short* __restrict__ apk,
                                                       const unsigned short* __restrict__ vpk,
                                                       float* __restrict__ out) {
  __shared__ unsigned short As[16384];      // 32 KB packed A panel
  __shared__ float colsum[256];             // 1 KB
  __shared__ float rowsum[64];              // 256 B

  const int tid = threadIdx.x;
  const int w = tid >> 6;          // 0..7
  const int h = w >> 2;            // 0..1 (row half: 32 rows)
  const int cq = w & 3;            // 0..3 (col quarter: 64 cols)
  const int lane = tid & 63;
  const int lo16 = lane & 15;
  const int q4 = lane >> 4;        // 0..3

  // 4096 blocks: xcd = id&7; per XCD 4 colblks (512 KB B hot-set, L2-resident),
  // consecutive t walk rowblks within a colblk.
  int id = blockIdx.x;
  int xcd = id & 7;
  int t = id >> 3;                      // 0..511
  int colblk = (xcd << 2) | (t & 3);    // 0..31  (256-col strip)
  int rowblk = t >> 2;                  // 0..127 (64-row panel)

  if (tid < 256) colsum[tid] = 0.0f;
  if (tid >= 256 && tid < 320) rowsum[tid - 256] = 0.0f;

  // ---- Stage A panel: 32 KB, pure linear copy of packed fragments ----
  const char* aP = (const char*)apk + (size_t)rowblk * 32768;
  #pragma unroll
  for (int u = 0; u < 4; ++u) {
    int chunk = w * 4 + u;                     // 0..31 (1-KB fragments)
    const char* src = aP + chunk * 1024 + lane * 16;
    unsigned short* dst = &As[chunk * 512];
    __builtin_amdgcn_global_load_lds((const __attribute__((address_space(1))) uint32_t*)src,
                                     (__attribute__((address_space(3))) uint32_t*)dst, 16, 0, 0);
  }

  // ---- B ping-pong prologue: wave's 4 col-panels (cp = colblk*16 + cq*4 + n),
  //      frag byte = n*8192 + ks*1024; steps 0 and 1 in flight ----
  const char* p0 = (const char*)vpk + (size_t)(colblk * 16 + cq * 4) * 8192 + lane * 16;

  short8 S[2][4];
  #pragma unroll
  for (int n = 0; n < 4; ++n) {
    S[0][n] = *(const short8*)(p0 + n * 8192);
    S[1][n] = *(const short8*)(p0 + n * 8192 + 1024);
  }

  asm volatile("s_waitcnt vmcnt(0)" ::: "memory");   // A-panel writes done
  __builtin_amdgcn_s_barrier();
  asm volatile("" ::: "memory");

  f32x4 acc[2][4];
  #pragma unroll
  for (int m = 0; m < 2; ++m)
    #pragma unroll
    for (int n = 0; n < 4; ++n)
      #pragma unroll
      for (int q = 0; q < 4; ++q)
        acc[m][n][q] = 0.0f;

  // ---- K loop: 8 static steps, no barriers. Wave h reads A fragments
  //      (h*2 + m); ping-pong slot ks&1 refilled for step ks+2. ----
  #pragma unroll
  for (int ks = 0; ks < 8; ++ks) {
    short8 af[2];
    #pragma unroll
    for (int m = 0; m < 2; ++m)
      af[m] = *(const short8*)((const char*)As + ((h * 2 + m) * 8 + ks) * 1024 + lane * 16);
    #pragma unroll
    for (int n = 0; n < 4; ++n)
      #pragma unroll
      for (int m = 0; m < 2; ++m)
        acc[m][n] = __builtin_amdgcn_mfma_f32_16x16x32_bf16(af[m], S[ks & 1][n], acc[m][n], 0, 0, 0);
    if (ks < 6) {                              // refill consumed slot for ks+2
      #pragma unroll
      for (int n = 0; n < 4; ++n)
        S[ks & 1][n] = *(const short8*)(p0 + n * 8192 + (ks + 2) * 1024);
    }
  }

  // ---- epilogue: E = exp2(acc); row/col partials -> LDS ds_add_f32.
  // C/D layout: col = n*16 + lo16, row = h*32 + m*16 + q4*4 + g.
  float colpart[4] = {0.f, 0.f, 0.f, 0.f};
  float rp[2][4];
  #pragma unroll
  for (int m = 0; m < 2; ++m)
    #pragma unroll
    for (int g = 0; g < 4; ++g)
      rp[m][g] = 0.0f;

  #pragma unroll
  for (int m = 0; m < 2; ++m)
    #pragma unroll
    for (int n = 0; n < 4; ++n)
      #pragma unroll
      for (int g = 0; g < 4; ++g) {
        float ev = __builtin_amdgcn_exp2f(acc[m][n][g]);
        rp[m][g] += ev;
        colpart[n] += ev;
      }

  // rows: reduce over 16 cols (lo16 group); lane lo16==m*4+g merges its
  // q4-group's row via LDS atomic (4 active lanes, distinct addresses)
  #pragma unroll
  for (int m = 0; m < 2; ++m)
    #pragma unroll
    for (int g = 0; g < 4; ++g) {
      float rs = rp[m][g];
      rs += __shfl_xor(rs, 1);
      rs += __shfl_xor(rs, 2);
      rs += __shfl_xor(rs, 4);
      rs += __shfl_xor(rs, 8);
      if (lo16 == m * 4 + g) {
        atomicAdd(&rowsum[h * 32 + m * 16 + q4 * 4 + g], rs);
      }
    }

  // cols: sum the 4 q4 copies (covers the wave's 32 rows); lane-group n
  // merges its 16 cols
  #pragma unroll
  for (int n = 0; n < 4; ++n) {
    float cs = colpart[n];
    cs += __shfl_xor(cs, 16);
    cs += __shfl_xor(cs, 32);
    if (q4 == n) {
      atomicAdd(&colsum[cq * 64 + n * 16 + lo16], cs);
    }
  }

  __syncthreads();

  // ---- tail: global atomics in one dependent-free burst ----
  if (tid < 256) {
    atomicAdd(&out[NB + colblk * 256 + tid], colsum[tid]);
  } else if (tid < 320) {
    atomicAdd(&out[rowblk * 64 + (tid - 256)], rowsum[tid - 256]);
  }
}

extern "C" void kernel_launch(void* const* d_in, const int* in_sizes, int n_in,
                              void* d_out, int out_size, void* d_ws, size_t ws_size,
                              hipStream_t stream) {
  const float* e = (const float*)d_in[0];
  const float* v = (const float*)d_in[1];
  float* out = (float*)d_out;
  unsigned short* apk = (unsigned short*)d_ws;                 // 4 MiB packed e
  unsigned short* vpk = apk + (size_t)NB * DK;                 // 4 MiB packed v
  hipLaunchKernelGGL(normpack_kernel, dim3((2 * NB) / 4), dim3(256), 0, stream, e, v, apk, vpk, out);
  hipLaunchKernelGGL(score_kernel, dim3(4096), dim3(512), 0, stream, apk, vpk, out);
}

// Round 15
// 74.815 us; speedup vs baseline: 1.0138x; 1.0138x over previous
//
#include <hip/hip_runtime.h>
#include <hip/hip_bf16.h>
#include <stdint.h>

#define NB 8192
#define DK 256
// gamma * log2(e): epilogue uses native exp2
#define GSCALE 14.426950408889634f

typedef short short8 __attribute__((ext_vector_type(8)));
typedef float f32x4 __attribute__((ext_vector_type(4)));

__device__ __forceinline__ unsigned short f32_to_bf16(float f) {
  uint32_t u = __builtin_bit_cast(uint32_t, f);
  u += 0x7FFFu + ((u >> 16) & 1u);   // RNE
  return (unsigned short)(u >> 16);
}

// Normalize (gamma*log2e folded into e side) AND write in PACKED MFMA-fragment
// layout: fragment (row-panel p = r>>4, ks = k>>5) is a contiguous 1-KB chunk;
// lane l owns bytes l*16..+16 = row p*16+(r&15), k = ks*32 + (l>>4)*8 ..+8.
// packed_byte(r,k) = (r>>4)*8192 + (k>>5)*1024 + ((k>>3)&3)*256 + (r&15)*16 + (k&7)*2.
// Blocks 0..15 also zero d_out (replaces hipMemsetAsync).
__global__ __launch_bounds__(256) void normpack_kernel(const float* __restrict__ e,
                                                       const float* __restrict__ v,
                                                       unsigned short* __restrict__ apk,
                                                       unsigned short* __restrict__ vpk,
                                                       float* __restrict__ out) {
  if (blockIdx.x < 16) {
    float4 z = {0.f, 0.f, 0.f, 0.f};
    reinterpret_cast<float4*>(out)[blockIdx.x * 256 + threadIdx.x] = z;
  }
  int wave = threadIdx.x >> 6;
  int lane = threadIdx.x & 63;
  int row = blockIdx.x * 4 + wave;          // 0..16383
  const float* src;
  unsigned short* dstbase;
  float mul;
  if (row < NB) {
    src = e + (size_t)row * DK; dstbase = apk; mul = GSCALE;
  } else {
    row -= NB;
    src = v + (size_t)row * DK; dstbase = vpk; mul = 1.0f;
  }
  float4 x = reinterpret_cast<const float4*>(src)[lane];   // k = 4*lane .. +3
  float ss = x.x * x.x + x.y * x.y + x.z * x.z + x.w * x.w;
  #pragma unroll
  for (int off = 32; off >= 1; off >>= 1) ss += __shfl_xor(ss, off);
  float s = mul / fmaxf(sqrtf(ss), 1e-8f);
  ushort4 o;
  o.x = f32_to_bf16(x.x * s);
  o.y = f32_to_bf16(x.y * s);
  o.z = f32_to_bf16(x.z * s);
  o.w = f32_to_bf16(x.w * s);
  size_t off = (size_t)(row >> 4) * 8192 + (size_t)(lane >> 3) * 1024 +
               ((lane >> 1) & 3) * 256 + (row & 15) * 16 + (lane & 1) * 8;
  *reinterpret_cast<ushort4*>((char*)dstbase + off) = o;
}

// R13 (best: 63us, clean codegen) with a j x2 STATIC unroll to amortize the
// per-block fixed costs (A-stage prologue ~700cyc + epilogue ~900cyc vs only
// 620cyc of MFMA -- the measured 21% MfmaUtil ceiling). Block = 64 rows x
// 512 cols, 4 waves; each wave: two sequential 64x64 tiles, 16 static
// K-steps, B ping-pong S[2][4] continuous across the tile boundary (tile-1
// frags in flight UNDER tile-0's epilogue). Row partials carried in regs
// across both tiles (row shfl-tree once per block). Cols: unique per
// (j,wave) -> plain LDS stores. All indices compile-time; no dynamic
// loop-carried ring (the R11/R12 spill trap).
__global__ __launch_bounds__(256, 3) void score_kernel(const unsigned short* __restrict__ apk,
                                                       const unsigned short* __restrict__ vpk,
                                                       float* __restrict__ out) {
  __shared__ unsigned short As[16384];      // 32 KB packed A panel
  __shared__ float colsum[512];             // 2 KB
  __shared__ float rowsum[4][64];           // 1 KB

  const int tid = threadIdx.x;
  const int w = tid >> 6;          // 0..3 (64-col group within each tile)
  const int lane = tid & 63;
  const int lo16 = lane & 15;
  const int q4 = lane >> 4;        // 0..3

  // 2048 blocks: xcd = id&7; 2 colblks per XCD (512 KB B hot-set, L2-resident);
  // consecutive t walk rowblks within a colblk.
  int id = blockIdx.x;
  int xcd = id & 7;
  int t = id >> 3;                      // 0..255
  int colblk = (xcd << 1) | (t & 1);    // 0..15  (512-col strip)
  int rowblk = t >> 1;                  // 0..127 (64-row panel)

  // ---- Stage A panel: 32 KB, pure linear copy of packed fragments ----
  const char* aP = (const char*)apk + (size_t)rowblk * 32768;
  #pragma unroll
  for (int u = 0; u < 8; ++u) {
    int chunk = w * 8 + u;                     // 0..31 (1-KB fragments)
    const char* src = aP + chunk * 1024 + lane * 16;
    unsigned short* dst = &As[chunk * 512];
    __builtin_amdgcn_global_load_lds((const __attribute__((address_space(1))) uint32_t*)src,
                                     (__attribute__((address_space(3))) uint32_t*)dst, 16, 0, 0);
  }

  // ---- B ping-pong prologue. Wave cols at tile j: colblk*512 + j*256 + w*64.
  //      Panel = colblk*32 + j*16 + w*4 + n; step g=j*8+ks:
  //      off(g,n) = (g>>3)*131072 + n*8192 + (g&7)*1024 from wave base. ----
  const char* pb = (const char*)vpk + (size_t)(colblk * 32 + w * 4) * 8192 + lane * 16;

  short8 S[2][4];
  #pragma unroll
  for (int n = 0; n < 4; ++n) {
    S[0][n] = *(const short8*)(pb + n * 8192);           // g=0
    S[1][n] = *(const short8*)(pb + n * 8192 + 1024);    // g=1
  }

  asm volatile("s_waitcnt vmcnt(0)" ::: "memory");   // A-panel + S ready
  __builtin_amdgcn_s_barrier();
  asm volatile("" ::: "memory");

  f32x4 acc[4][4];
  #pragma unroll
  for (int m = 0; m < 4; ++m)
    #pragma unroll
    for (int n = 0; n < 4; ++n)
      #pragma unroll
      for (int q = 0; q < 4; ++q)
        acc[m][n][q] = 0.0f;

  float rp[4][4];                      // row partials, carried across both tiles
  #pragma unroll
  for (int m = 0; m < 4; ++m)
    #pragma unroll
    for (int g = 0; g < 4; ++g)
      rp[m][g] = 0.0f;

  #pragma unroll
  for (int j = 0; j < 2; ++j) {
    // ---- 8 static K-steps for tile j (flat step g = j*8 + ks) ----
    #pragma unroll
    for (int ks = 0; ks < 8; ++ks) {
      const int g = j * 8 + ks;
      short8 af[4];
      #pragma unroll
      for (int m = 0; m < 4; ++m)
        af[m] = *(const short8*)((const char*)As + (m * 8 + ks) * 1024 + lane * 16);
      #pragma unroll
      for (int n = 0; n < 4; ++n)
        #pragma unroll
        for (int m = 0; m < 4; ++m)
          acc[m][n] = __builtin_amdgcn_mfma_f32_16x16x32_bf16(af[m], S[g & 1][n], acc[m][n], 0, 0, 0);
      if (g < 14) {                            // refill consumed slot for step g+2
        const int gp = g + 2;
        #pragma unroll
        for (int n = 0; n < 4; ++n)
          S[g & 1][n] = *(const short8*)(pb + (gp >> 3) * 131072 + n * 8192 + (gp & 7) * 1024);
      }
    }

    // ---- tile-j epilogue (next tile's first frags already in flight):
    // E = exp2(acc); rows -> rp regs, cols -> plain LDS store (unique owner).
    // C/D layout: col = n*16 + lo16, row = m*16 + q4*4 + g2.
    float colpart[4] = {0.f, 0.f, 0.f, 0.f};
    #pragma unroll
    for (int m = 0; m < 4; ++m)
      #pragma unroll
      for (int n = 0; n < 4; ++n)
        #pragma unroll
        for (int g2 = 0; g2 < 4; ++g2) {
          float ev = __builtin_amdgcn_exp2f(acc[m][n][g2]);
          rp[m][g2] += ev;
          colpart[n] += ev;
          acc[m][n][g2] = 0.0f;
        }
    #pragma unroll
    for (int n = 0; n < 4; ++n) {
      float cs = colpart[n];
      cs += __shfl_xor(cs, 16);
      cs += __shfl_xor(cs, 32);
      if (q4 == n) {
        colsum[j * 256 + w * 64 + n * 16 + lo16] = cs;   // written exactly once
      }
    }
  }

  // ---- rows (once per block): reduce over 16 cols; lane lo16==m*4+g holds
  //      row m*16 + q4*4 + g ----
  #pragma unroll
  for (int m = 0; m < 4; ++m)
    #pragma unroll
    for (int g = 0; g < 4; ++g) {
      float rs = rp[m][g];
      rs += __shfl_xor(rs, 1);
      rs += __shfl_xor(rs, 2);
      rs += __shfl_xor(rs, 4);
      rs += __shfl_xor(rs, 8);
      if (lo16 == m * 4 + g) {
        rowsum[w][m * 16 + q4 * 4 + g] = rs;
      }
    }

  __syncthreads();

  // ---- tail: global atomics in one dependent-free burst ----
  atomicAdd(&out[NB + colblk * 512 + tid], colsum[tid]);
  atomicAdd(&out[NB + colblk * 512 + 256 + tid], colsum[256 + tid]);
  if (tid < 64) {
    float s = rowsum[0][tid] + rowsum[1][tid] + rowsum[2][tid] + rowsum[3][tid];
    atomicAdd(&out[rowblk * 64 + tid], s);
  }
}

extern "C" void kernel_launch(void* const* d_in, const int* in_sizes, int n_in,
                              void* d_out, int out_size, void* d_ws, size_t ws_size,
                              hipStream_t stream) {
  const float* e = (const float*)d_in[0];
  const float* v = (const float*)d_in[1];
  float* out = (float*)d_out;
  unsigned short* apk = (unsigned short*)d_ws;                 // 4 MiB packed e
  unsigned short* vpk = apk + (size_t)NB * DK;                 // 4 MiB packed v
  hipLaunchKernelGGL(normpack_kernel, dim3((2 * NB) / 4), dim3(256), 0, stream, e, v, apk, vpk, out);
  hipLaunchKernelGGL(score_kernel, dim3(2048), dim3(256), 0, stream, apk, vpk, out);
}

// Round 16
// 58.006 us; speedup vs baseline: 1.3076x; 1.2898x over previous
//
#include <hip/hip_runtime.h>
#include <hip/hip_bf16.h>
#include <stdint.h>

#define NB 8192
#define DK 256
// gamma * log2(e): epilogue uses native exp2
#define GSCALE 14.426950408889634f

typedef short short8 __attribute__((ext_vector_type(8)));
typedef float f32x4 __attribute__((ext_vector_type(4)));

__device__ __forceinline__ unsigned short f32_to_bf16(float f) {
  uint32_t u = __builtin_bit_cast(uint32_t, f);
  u += 0x7FFFu + ((u >> 16) & 1u);   // RNE
  return (unsigned short)(u >> 16);
}

// Normalize (gamma*log2e folded into e side) AND write in PACKED MFMA-fragment
// layout: fragment (row-panel p = r>>4, ks = k>>5) is a contiguous 1-KB chunk;
// lane l owns bytes l*16..+16 = row p*16+(r&15), k = ks*32 + (l>>4)*8 ..+8.
// packed_byte(r,k) = (r>>4)*8192 + (k>>5)*1024 + ((k>>3)&3)*256 + (r&15)*16 + (k&7)*2.
// Blocks 0..15 also zero d_out (replaces hipMemsetAsync).
__global__ __launch_bounds__(256) void normpack_kernel(const float* __restrict__ e,
                                                       const float* __restrict__ v,
                                                       unsigned short* __restrict__ apk,
                                                       unsigned short* __restrict__ vpk,
                                                       float* __restrict__ out) {
  if (blockIdx.x < 16) {
    float4 z = {0.f, 0.f, 0.f, 0.f};
    reinterpret_cast<float4*>(out)[blockIdx.x * 256 + threadIdx.x] = z;
  }
  int wave = threadIdx.x >> 6;
  int lane = threadIdx.x & 63;
  int row = blockIdx.x * 4 + wave;          // 0..16383
  const float* src;
  unsigned short* dstbase;
  float mul;
  if (row < NB) {
    src = e + (size_t)row * DK; dstbase = apk; mul = GSCALE;
  } else {
    row -= NB;
    src = v + (size_t)row * DK; dstbase = vpk; mul = 1.0f;
  }
  float4 x = reinterpret_cast<const float4*>(src)[lane];   // k = 4*lane .. +3
  float ss = x.x * x.x + x.y * x.y + x.z * x.z + x.w * x.w;
  #pragma unroll
  for (int off = 32; off >= 1; off >>= 1) ss += __shfl_xor(ss, off);
  float s = mul / fmaxf(sqrtf(ss), 1e-8f);
  ushort4 o;
  o.x = f32_to_bf16(x.x * s);
  o.y = f32_to_bf16(x.y * s);
  o.z = f32_to_bf16(x.z * s);
  o.w = f32_to_bf16(x.w * s);
  size_t off = (size_t)(row >> 4) * 8192 + (size_t)(lane >> 3) * 1024 +
               ((lane >> 1) & 3) * 256 + (row & 15) * 16 + (lane & 1) * 8;
  *reinterpret_cast<ushort4*>((char*)dstbase + off) = o;
}

// R13 base (best: 63us, clean codegen) with three latency probes, epilogue
// frozen: (1) B ring depth 3 (S[3][4], static g%3 indices -- slack 3 K-steps
// > L2 latency); (2) counted prologue wait: A-glds / sched_barrier / B-loads,
// then s_waitcnt vmcnt(12) waits ONLY the 8 A-glds (B prologue loads fly
// through the barrier, m135 oldest-N semantics); (3) s_setprio(1) around the
// MFMA cluster (desynced-wave regime, m191). Block = 64 rows x 256 cols,
// 4 waves x (64x64 tile); A panel packed in LDS (linear copy, conflict-free
// by construction); no in-loop barriers; fully static body (no spill).
__global__ __launch_bounds__(256, 3) void score_kernel(const unsigned short* __restrict__ apk,
                                                       const unsigned short* __restrict__ vpk,
                                                       float* __restrict__ out) {
  __shared__ unsigned short As[16384];      // 32 KB packed A panel
  __shared__ float rowsum[4][64];           // 1 KB

  const int tid = threadIdx.x;
  const int w = tid >> 6;          // 0..3 (64-col group within block)
  const int lane = tid & 63;
  const int lo16 = lane & 15;
  const int q4 = lane >> 4;        // 0..3

  // 4096 blocks: xcd = id&7; per XCD 4 colblks (512 KB B hot-set, L2-resident),
  // consecutive t walk rowblks within a colblk.
  int id = blockIdx.x;
  int xcd = id & 7;
  int t = id >> 3;                      // 0..511
  int colblk = (xcd << 2) | (t & 3);    // 0..31  (256-col strip)
  int rowblk = t >> 2;                  // 0..127 (64-row panel)

  // ---- Stage A panel: 32 KB, pure linear copy of packed fragments ----
  const char* aP = (const char*)apk + (size_t)rowblk * 32768;
  #pragma unroll
  for (int u = 0; u < 8; ++u) {
    int chunk = w * 8 + u;                     // 0..31 (1-KB fragments)
    const char* src = aP + chunk * 1024 + lane * 16;
    unsigned short* dst = &As[chunk * 512];
    __builtin_amdgcn_global_load_lds((const __attribute__((address_space(1))) uint32_t*)src,
                                     (__attribute__((address_space(3))) uint32_t*)dst, 16, 0, 0);
  }
  __builtin_amdgcn_sched_barrier(0);   // pin issue order: glds first, B loads after

  // ---- B ring prologue: wave's 4 col-panels (cp = colblk*16 + w*4 + n),
  //      frag byte = n*8192 + ks*1024; ks = 0,1,2 in flight (12 loads) ----
  const char* p0 = (const char*)vpk + (size_t)(colblk * 16 + w * 4) * 8192 + lane * 16;

  short8 S[3][4];
  #pragma unroll
  for (int s = 0; s < 3; ++s)
    #pragma unroll
    for (int n = 0; n < 4; ++n)
      S[s][n] = *(const short8*)(p0 + n * 8192 + s * 1024);

  // wait ONLY the 8 A-glds (oldest 8 of 20 outstanding); B loads stay in flight
  asm volatile("s_waitcnt vmcnt(12)" ::: "memory");
  __builtin_amdgcn_s_barrier();
  asm volatile("" ::: "memory");

  f32x4 acc[4][4];
  #pragma unroll
  for (int m = 0; m < 4; ++m)
    #pragma unroll
    for (int n = 0; n < 4; ++n)
      #pragma unroll
      for (int q = 0; q < 4; ++q)
        acc[m][n][q] = 0.0f;

  // ---- K loop: 8 static steps, no barriers. 3-deep ring: step ks consumes
  //      S[ks%3]; refilled for step ks+3 (slack 3 steps > L2 latency). ----
  #pragma unroll
  for (int ks = 0; ks < 8; ++ks) {
    short8 af[4];
    #pragma unroll
    for (int m = 0; m < 4; ++m)
      af[m] = *(const short8*)((const char*)As + (m * 8 + ks) * 1024 + lane * 16);
    __builtin_amdgcn_s_setprio(1);
    #pragma unroll
    for (int n = 0; n < 4; ++n)
      #pragma unroll
      for (int m = 0; m < 4; ++m)
        acc[m][n] = __builtin_amdgcn_mfma_f32_16x16x32_bf16(af[m], S[ks % 3][n], acc[m][n], 0, 0, 0);
    __builtin_amdgcn_s_setprio(0);
    if (ks < 5) {                              // refill consumed slot for ks+3
      #pragma unroll
      for (int n = 0; n < 4; ++n)
        S[ks % 3][n] = *(const short8*)(p0 + n * 8192 + (ks + 3) * 1024);
    }
  }

  // ---- epilogue (identical to R13): E = exp2(acc); rows -> LDS merge,
  // cols -> atomics. C/D layout: col = n*16 + lo16, row = m*16 + q4*4 + g.
  float colpart[4] = {0.f, 0.f, 0.f, 0.f};
  float rp[4][4];
  #pragma unroll
  for (int m = 0; m < 4; ++m)
    #pragma unroll
    for (int g = 0; g < 4; ++g)
      rp[m][g] = 0.0f;

  #pragma unroll
  for (int m = 0; m < 4; ++m)
    #pragma unroll
    for (int n = 0; n < 4; ++n)
      #pragma unroll
      for (int g = 0; g < 4; ++g) {
        float ev = __builtin_amdgcn_exp2f(acc[m][n][g]);
        rp[m][g] += ev;
        colpart[n] += ev;
      }

  // rows: reduce over the 16 cols of each group; lane lo16==m*4+g holds
  // row m*16 + q4*4 + g
  #pragma unroll
  for (int m = 0; m < 4; ++m)
    #pragma unroll
    for (int g = 0; g < 4; ++g) {
      float rs = rp[m][g];
      rs += __shfl_xor(rs, 1);
      rs += __shfl_xor(rs, 2);
      rs += __shfl_xor(rs, 4);
      rs += __shfl_xor(rs, 8);
      if (lo16 == m * 4 + g) {
        rowsum[w][m * 16 + q4 * 4 + g] = rs;
      }
    }

  // cols: colpart[n] covers q4's 16 rows; sum the 4 q4 copies, lane-group n
  // writes its 16 cols
  #pragma unroll
  for (int n = 0; n < 4; ++n) {
    float cs = colpart[n];
    cs += __shfl_xor(cs, 16);
    cs += __shfl_xor(cs, 32);
    if (q4 == n) {
      atomicAdd(&out[NB + colblk * 256 + w * 64 + n * 16 + lo16], cs);
    }
  }

  __syncthreads();
  // rows: merge the 4 waves' copies (same 64 rows), one atomic per row
  if (tid < 64) {
    float s = rowsum[0][tid] + rowsum[1][tid] + rowsum[2][tid] + rowsum[3][tid];
    atomicAdd(&out[rowblk * 64 + tid], s);
  }
}

extern "C" void kernel_launch(void* const* d_in, const int* in_sizes, int n_in,
                              void* d_out, int out_size, void* d_ws, size_t ws_size,
                              hipStream_t stream) {
  const float* e = (const float*)d_in[0];
  const float* v = (const float*)d_in[1];
  float* out = (float*)d_out;
  unsigned short* apk = (unsigned short*)d_ws;                 // 4 MiB packed e
  unsigned short* vpk = apk + (size_t)NB * DK;                 // 4 MiB packed v
  hipLaunchKernelGGL(normpack_kernel, dim3((2 * NB) / 4), dim3(256), 0, stream, e, v, apk, vpk, out);
  hipLaunchKernelGGL(score_kernel, dim3(4096), dim3(256), 0, stream, apk, vpk, out);
}